// Round 4
// baseline (48.873 us; speedup 1.0000x reference)
//
#include <hip/hip_runtime.h>
#include <hip/hip_bf16.h>

#define H 2048
#define RIN 2304
#define SW 256
#define SD 200

// ws layout (floats):
#define WS_CDOT 0
#define WS_SDOT 4
#define WS_GH0  260
#define WS_GH1  6404
#define WS_GI0  12548

// out layout (floats): [0..100) logits, [100..2148) h0, [2148..4196) h1,
// [4196..55396) new_stack (200x256)

typedef __attribute__((ext_vector_type(4))) float f32x4;

__device__ __forceinline__ float wave_reduce(float acc) {
  #pragma unroll
  for (int off = 32; off > 0; off >>= 1) acc += __shfl_down(acc, off);
  return acc;  // valid in lane 0
}

__device__ __forceinline__ float sigmoidf(float x) {
  return 1.f / (1.f + expf(-x));
}

// R-row dot product, chunked over K in 256-float chunks, software-pipelined
// one chunk ahead. Long-lived wave: loads for chunk k+1 issue while chunk k's
// FMAs retire -> continuous memory-level parallelism across the wave's whole
// lifetime (R1-R3 showed one-shot burst-per-wave stays latency-bound at
// ~12 GB/s/CU regardless of per-burst ILP).
template <int R>
__device__ __forceinline__ void dot_rows(const float* __restrict__ W, size_t ldw,
                                         const float* __restrict__ x, int nchunk,
                                         float* part) {
  int lane = threadIdx.x & 63;
  const f32x4* x4 = (const f32x4*)x;
  const f32x4* wp[R];
  f32x4 acc[R], a[R];
  #pragma unroll
  for (int r = 0; r < R; ++r) {
    wp[r] = (const f32x4*)(W + (size_t)r * ldw);
    acc[r] = (f32x4)(0.f);
  }
  f32x4 xb = x4[lane];
  #pragma unroll
  for (int r = 0; r < R; ++r) a[r] = wp[r][lane];
  for (int k = 1; k < nchunk; ++k) {
    f32x4 xn = x4[k * 64 + lane];
    f32x4 an[R];
    #pragma unroll
    for (int r = 0; r < R; ++r) an[r] = wp[r][k * 64 + lane];
    #pragma unroll
    for (int r = 0; r < R; ++r) acc[r] += a[r] * xb;
    xb = xn;
    #pragma unroll
    for (int r = 0; r < R; ++r) a[r] = an[r];
  }
  #pragma unroll
  for (int r = 0; r < R; ++r) acc[r] += a[r] * xb;
  #pragma unroll
  for (int r = 0; r < R; ++r) part[r] = acc[r][0] + acc[r][1] + acc[r][2] + acc[r][3];
}

// K1: all input-only matvecs. One wave = 4 rows (3 for cdot).
// waves: [0,1536) gh0 ; [1536,3072) gh1 ; [3072,4608) gi0 ;
//        [4608,4672) sdot (K=4096) ; 4672 cdot (R=3, K=4096)
__global__ __launch_bounds__(256)
void k1_matvecs(const float* __restrict__ hidden, const int* __restrict__ inp,
                const float* __restrict__ emb,
                const float* __restrict__ Wc, const float* __restrict__ bc,
                const float* __restrict__ Ws, const float* __restrict__ bs,
                const float* __restrict__ Wih0, const float* __restrict__ bih0,
                const float* __restrict__ Whh0, const float* __restrict__ bhh0,
                const float* __restrict__ Whh1, const float* __restrict__ bhh1,
                float* __restrict__ ws) {
  int w = blockIdx.x * 4 + (threadIdx.x >> 6);
  int lane = threadIdx.x & 63;
  if (w > 4672) return;
  float part[4];
  if (w < 1536) {
    int row = w * 4;
    dot_rows<4>(Whh0 + (size_t)row * H, H, hidden, 8, part);
    #pragma unroll
    for (int r = 0; r < 4; ++r) {
      float d = wave_reduce(part[r]);
      if (lane == 0) ws[WS_GH0 + row + r] = d + bhh0[row + r];
    }
  } else if (w < 3072) {
    int row = (w - 1536) * 4;
    dot_rows<4>(Whh1 + (size_t)row * H, H, hidden + H, 8, part);
    #pragma unroll
    for (int r = 0; r < 4; ++r) {
      float d = wave_reduce(part[r]);
      if (lane == 0) ws[WS_GH1 + row + r] = d + bhh1[row + r];
    }
  } else if (w < 4608) {
    int row = (w - 3072) * 4;
    const float* erow = emb + (size_t)inp[0] * H;
    dot_rows<4>(Wih0 + (size_t)row * RIN, RIN, erow, 8, part);
    #pragma unroll
    for (int r = 0; r < 4; ++r) {
      float d = wave_reduce(part[r]);
      if (lane == 0) ws[WS_GI0 + row + r] = d + bih0[row + r];
    }
  } else if (w < 4672) {
    int row = (w - 4608) * 4;
    dot_rows<4>(Ws + (size_t)row * (2 * H), 2 * H, hidden, 16, part);
    #pragma unroll
    for (int r = 0; r < 4; ++r) {
      float d = wave_reduce(part[r]);
      if (lane == 0) ws[WS_SDOT + row + r] = d + bs[r + row];
    }
  } else {
    dot_rows<3>(Wc, 2 * H, hidden, 16, part);
    #pragma unroll
    for (int r = 0; r < 3; ++r) {
      float d = wave_reduce(part[r]);
      if (lane == 0) ws[WS_CDOT + r] = d + bc[r];
    }
  }
}

// K2: blocks [0,2048): GRU layer0 finish (one j per block; 3 waves do the
//     K=256 stack-column dots of Wih0); blocks [2048,2248): new_stack rows.
__global__ __launch_bounds__(256)
void k2_stack_gru0(const float* __restrict__ stack,
                   const float* __restrict__ hidden,
                   const float* __restrict__ Wih0,
                   const float* __restrict__ ws,
                   float* out) {
  int t = threadIdx.x;
  float c0 = ws[WS_CDOT + 0], c1 = ws[WS_CDOT + 1], c2 = ws[WS_CDOT + 2];
  float m = fmaxf(c0, fmaxf(c1, c2));
  float e0 = expf(c0 - m), e1 = expf(c1 - m), e2 = expf(c2 - m);
  float inv = 1.f / (e0 + e1 + e2);
  float a_push = e0 * inv, a_pop = e1 * inv, a_noop = e2 * inv;

  int b = blockIdx.x;
  if (b >= 2048) {
    int r = b - 2048;
    float up = (r == 0) ? tanhf(ws[WS_SDOT + t]) : stack[(r - 1) * SW + t];
    float down = (r == SD - 1) ? 0.f : stack[(r + 1) * SW + t];
    out[4196 + r * SW + t] = a_noop * stack[r * SW + t] + a_push * up + a_pop * down;
    return;
  }
  __shared__ float st[SW];
  __shared__ float gred[3];
  st[t] = a_noop * stack[t] + a_push * tanhf(ws[WS_SDOT + t]) + a_pop * stack[SW + t];
  __syncthreads();
  int wv = t >> 6, lane = t & 63;
  int j = b;
  if (wv < 3) {
    const f32x4* w4 = (const f32x4*)(Wih0 + (size_t)(wv * H + j) * RIN + H);
    const f32x4* s4 = (const f32x4*)st;
    f32x4 a = w4[lane];
    f32x4 xv = s4[lane];
    f32x4 p = a * xv;
    float acc = wave_reduce(p[0] + p[1] + p[2] + p[3]);
    if (lane == 0) gred[wv] = acc;
  }
  __syncthreads();
  if (t == 0) {
    float gr = ws[WS_GI0 + j] + gred[0] + ws[WS_GH0 + j];
    float gz = ws[WS_GI0 + H + j] + gred[1] + ws[WS_GH0 + H + j];
    float r = sigmoidf(gr);
    float z = sigmoidf(gz);
    float n = tanhf(ws[WS_GI0 + 2 * H + j] + gred[2] + r * ws[WS_GH0 + 2 * H + j]);
    out[100 + j] = (1.f - z) * n + z * hidden[j];
  }
}

// K3: GRU layer1. One wave = one j: all 3 gate rows (r,z,n) in one dot_rows<3>,
// no LDS, no syncthreads. 512 blocks x 4 waves.
__global__ __launch_bounds__(256)
void k3_gru1(const float* __restrict__ hidden,
             const float* __restrict__ Wih1, const float* __restrict__ bih1,
             const float* __restrict__ ws,
             float* out) {
  int j = blockIdx.x * 4 + (threadIdx.x >> 6);
  int lane = threadIdx.x & 63;
  if (j >= H) return;
  const float* h0 = out + 100;  // written by k2
  float part[3];
  dot_rows<3>(Wih1 + (size_t)j * H, (size_t)H * H, h0, 8, part);
  float pr = wave_reduce(part[0]);
  float pz = wave_reduce(part[1]);
  float pn = wave_reduce(part[2]);
  if (lane == 0) {
    float r = sigmoidf(pr + bih1[j] + ws[WS_GH1 + j]);
    float z = sigmoidf(pz + bih1[H + j] + ws[WS_GH1 + H + j]);
    float n = tanhf(pn + bih1[2 * H + j] + r * ws[WS_GH1 + 2 * H + j]);
    out[100 + H + j] = (1.f - z) * n + z * hidden[H + j];
  }
}

// K4: logits = Wd @ h1 + bd. One wave = 4 rows, 25 waves.
__global__ __launch_bounds__(256)
void k4_logits(const float* __restrict__ Wd, const float* __restrict__ bd,
               float* out) {
  int w = blockIdx.x * 4 + (threadIdx.x >> 6);
  int lane = threadIdx.x & 63;
  if (w >= 25) return;
  const float* h1 = out + 100 + H;  // written by k3
  int row = w * 4;
  float part[4];
  dot_rows<4>(Wd + (size_t)row * H, H, h1, 8, part);
  #pragma unroll
  for (int r = 0; r < 4; ++r) {
    float d = wave_reduce(part[r]);
    if (lane == 0) out[row + r] = d + bd[row + r];
  }
}

extern "C" void kernel_launch(void* const* d_in, const int* in_sizes, int n_in,
                              void* d_out, int out_size, void* d_ws, size_t ws_size,
                              hipStream_t stream) {
  const int*   inp    = (const int*)d_in[0];
  const float* hidden = (const float*)d_in[1];
  const float* stack  = (const float*)d_in[2];
  const float* emb    = (const float*)d_in[3];
  const float* Wc     = (const float*)d_in[4];
  const float* bc     = (const float*)d_in[5];
  const float* Ws     = (const float*)d_in[6];
  const float* bs     = (const float*)d_in[7];
  const float* Wih0   = (const float*)d_in[8];
  const float* Whh0   = (const float*)d_in[9];
  const float* bih0   = (const float*)d_in[10];
  const float* bhh0   = (const float*)d_in[11];
  const float* Wih1   = (const float*)d_in[12];
  const float* Whh1   = (const float*)d_in[13];
  const float* bih1   = (const float*)d_in[14];
  const float* bhh1   = (const float*)d_in[15];
  const float* Wd     = (const float*)d_in[16];
  const float* bd     = (const float*)d_in[17];
  float* ws  = (float*)d_ws;
  float* out = (float*)d_out;

  k1_matvecs<<<1169, 256, 0, stream>>>(hidden, inp, emb, Wc, bc, Ws, bs,
                                       Wih0, bih0, Whh0, bhh0, Whh1, bhh1, ws);
  k2_stack_gru0<<<2248, 256, 0, stream>>>(stack, hidden, Wih0, ws, out);
  k3_gru1<<<512, 256, 0, stream>>>(hidden, Wih1, bih1, ws, out);
  k4_logits<<<7, 256, 0, stream>>>(Wd, bd, out);
}